// Round 10
// baseline (46.195 us; speedup 1.0000x reference)
//
#include <hip/hip_runtime.h>
#include <hip/hip_bf16.h>

// Masked SDPA, B=16, NQ=2048, NKV=2048, D=64, f32 in/out, bf16 MFMA compute.
// R10: dynamic load balancing. R7/R8/R9 all ~40 us despite different micro-
// structures => bottleneck is the partition: longest-batch CUs run 16 serial
// iters while short-batch CUs idle (vlen ~ U[0,2048)). New partition:
// block = 8 waves = 2 qsub(32q) x 4 KV-quarters (tiles interleaved stride 4),
// grid 512, <=8 iters/block; HW dispatcher refills CUs as blocks finish ->
// makespan ~ mean not max. 4-way merge in padded LDS, shuffle-free epilogue.
// Body kept from R9: reg-direct loads from fragment-sequential ws (no LDS, no
// barriers in loop), 32x32 swapped QK^T, in-register P (cvt_pk + permlane32),
// T13 defer-max, K-prefetch reg double-buffer. Mask fast-path for full tiles.

typedef __attribute__((ext_vector_type(8))) short short8;
typedef __attribute__((ext_vector_type(4))) short short4v;
typedef __attribute__((ext_vector_type(4))) float float4v;
typedef __attribute__((ext_vector_type(16))) float f32x16;

#define BATCH 16
#define NQ 2048
#define NKV 2048
#define DH 64
#define KVB 64
#define NTILES (NKV / KVB)          // 32
#define TILE_ELEMS (KVB * DH)       // 4096 bf16 = 8 KB per tile per array
#define NEG_INF -1e20f
// (1/sqrt(64)) * log2(e)
#define SCALE_LOG2 0.180336880111120f

__device__ __forceinline__ short f2bf(float x) {
    union { float f; unsigned u; } v; v.f = x;
    unsigned r = (v.u + 0x7fffu + ((v.u >> 16) & 1u)) >> 16;
    return (short)r;
}

__device__ __forceinline__ short8 cvt8(float4v a, float4v b) {
    short8 r;
    r[0] = f2bf(a[0]); r[1] = f2bf(a[1]); r[2] = f2bf(a[2]); r[3] = f2bf(a[3]);
    r[4] = f2bf(b[0]); r[5] = f2bf(b[1]); r[6] = f2bf(b[2]); r[7] = f2bf(b[3]);
    return r;
}

// ---- prep: f32 -> bf16 fragment-sequential layouts --------------------------
// Kf[b][tile][(s*4+kk)*64+lane]*8 : lane(l31,hi) = K[kv=s*32+l31][d=kk*16+hi*8+j]
// Vf[b][tile][(t*4+ks)*64+lane]*8 : lane(l31,hi) = V^T[d=t*32+l31][kv=ks*16+hi*8+j]
__global__ __launch_bounds__(256) void prep_kernel(
    const float* __restrict__ K, const float* __restrict__ V,
    const int* __restrict__ valid_lens,
    short* __restrict__ Kf, short* __restrict__ Vf)
{
    const int b    = blockIdx.x >> 5;
    const int tile = blockIdx.x & 31;
    const int vlen = valid_lens[b];
    const int nkv  = (vlen == 0) ? NKV : vlen;
    if (tile * KVB >= nkv) return;          // never read by attn

    const int tid = threadIdx.x;
    const int ln  = tid & 63;
    const int l31 = ln & 31;
    const int hi8 = (ln >> 5) * 8;
    const size_t gbase = ((size_t)b * NKV + (size_t)tile * KVB) * DH;
    short* kt = Kf + (((size_t)b * NTILES + tile) * TILE_ELEMS);
    short* vt = Vf + (((size_t)b * NTILES + tile) * TILE_ELEMS);

#pragma unroll
    for (int s = 0; s < 2; ++s) {           // K frags: slots s*256+tid
        const int kk = tid >> 6;            // 0..3
        const int kv = s * 32 + l31;
        const int d  = kk * 16 + hi8;
        const float* p = K + gbase + (size_t)kv * DH + d;
        *reinterpret_cast<short8*>(kt + (s * 256 + tid) * 8) =
            cvt8(*reinterpret_cast<const float4v*>(p),
                 *reinterpret_cast<const float4v*>(p + 4));
    }
    {   // V: 4x4 float4 transpose -> short4 writes into frag-sequential layout
        const int kv0 = (tid >> 4) << 2;    // 0..60 step 4
        const int d0  = (tid & 15) << 2;    // 0..60 step 4
        const float* p = V + gbase + (size_t)kv0 * DH + d0;
        float4v r0 = *reinterpret_cast<const float4v*>(p);
        float4v r1 = *reinterpret_cast<const float4v*>(p + DH);
        float4v r2 = *reinterpret_cast<const float4v*>(p + 2 * DH);
        float4v r3 = *reinterpret_cast<const float4v*>(p + 3 * DH);
        const int ks  = kv0 >> 4;
        const int hiv = (kv0 >> 3) & 1;
        const int j0  = kv0 & 7;            // 0 or 4
#pragma unroll
        for (int k = 0; k < 4; ++k) {
            const int d    = d0 + k;
            const int lanev = (d & 31) + 32 * hiv;
            short4v w;
            w[0] = f2bf(r0[k]); w[1] = f2bf(r1[k]);
            w[2] = f2bf(r2[k]); w[3] = f2bf(r3[k]);
            *reinterpret_cast<short4v*>(
                vt + (((d >> 5) * 4 + ks) * 64 + lanev) * 8 + j0) = w;
        }
    }
}

// --------- attn: 8 waves = 2 qsub(32 q-rows) x 4 KV-quarters ----------------
__global__ __launch_bounds__(512) void attn_fwd_kernel(
    const float* __restrict__ Q,
    const short* __restrict__ Kf,
    const short* __restrict__ Vf,
    const int* __restrict__ valid_lens,
    float* __restrict__ O)
{
    __shared__ float  mrg[2][4][32][68];   // [qsub][kvq][q][d] pad->68 (~70KB)
    __shared__ float2 mlb[2][4][32];

    const int tid  = threadIdx.x;
    const int wave = tid >> 6;
    const int lane = tid & 63;
    const int l31  = lane & 31;
    const int hi   = lane >> 5;
    const int qsub = wave >> 2;            // 0..1
    const int kvq  = wave & 3;             // KV quarter

    const int b  = blockIdx.x & 15;        // XCD x initially caches batches
    const int qt = blockIdx.x >> 4;        // {x, x+8} (~4MB KV, fits L2)
    const int qbase = qt * 64 + qsub * 32;

    const int vlen  = valid_lens[b];
    const int nkv   = (vlen == 0) ? NKV : vlen;
    const int tiles = (nkv + KVB - 1) / KVB;
    const int nh    = (tiles - kvq + 3) >> 2;  // my quarter's tiles (stride 4)

    // Q B-fragments (scale folded): lane col q=l31, k-elems d = kk*16+hi*8+j
    const float* Qb = Q + ((size_t)b * NQ + qbase + l31) * DH;
    short8 qfrag[4];
#pragma unroll
    for (int kk = 0; kk < 4; ++kk) {
        const float* p = Qb + kk * 16 + hi * 8;
        float4v a = *reinterpret_cast<const float4v*>(p);
        float4v c = *reinterpret_cast<const float4v*>(p + 4);
#pragma unroll
        for (int j = 0; j < 4; ++j) { a[j] *= SCALE_LOG2; c[j] *= SCALE_LOG2; }
        qfrag[kk] = cvt8(a, c);
    }

    const short* Kfb = Kf + (size_t)b * NTILES * TILE_ELEMS + lane * 8;
    const short* Vfb = Vf + (size_t)b * NTILES * TILE_ELEMS + lane * 8;

    auto load_k = [&](short8 (&kf)[8], int tile) {
        const short* p = Kfb + (size_t)tile * TILE_ELEMS;
#pragma unroll
        for (int i = 0; i < 8; ++i)
            kf[i] = *reinterpret_cast<const short8*>(p + i * 512);
    };
    auto load_v = [&](short8 (&vf)[8], int tile) {
        const short* p = Vfb + (size_t)tile * TILE_ELEMS;
#pragma unroll
        for (int i = 0; i < 8; ++i)
            vf[i] = *reinterpret_cast<const short8*>(p + i * 512);
    };

    f32x16 acc_o[2];
#pragma unroll
    for (int t = 0; t < 2; ++t)
#pragma unroll
        for (int r = 0; r < 16; ++r) acc_o[t][r] = 0.f;
    float m = -INFINITY, lsum = 0.f;

    short8 kf0[8], kf1[8], vfr[8];

    auto body = [&](short8 (&kc)[8], short8 (&kn)[8], int it) {
        const int tile = 4 * it + kvq;
        load_v(vfr, tile);                 // issue early; used after softmax

        // ---- S^T = K Q^T: lane owns q=l31, kv = 32s + (r&3)+8(r>>2)+4hi ----
        f32x16 acs[2];
#pragma unroll
        for (int s = 0; s < 2; ++s)
#pragma unroll
            for (int r = 0; r < 16; ++r) acs[s][r] = 0.f;
        __builtin_amdgcn_s_setprio(1);
#pragma unroll
        for (int s = 0; s < 2; ++s)
#pragma unroll
            for (int kk = 0; kk < 4; ++kk)
                acs[s] = __builtin_amdgcn_mfma_f32_32x32x16_bf16(
                    kc[s * 4 + kk], qfrag[kk], acs[s], 0, 0, 0);
        __builtin_amdgcn_s_setprio(0);

        if (it + 1 < nh) load_k(kn, 4 * (it + 1) + kvq);  // prefetch next K

        // ---- mask, skipped for fully-valid tiles (wave-uniform) ----
        if (vlen < (tile + 1) * KVB) {
            const int kvb0 = tile * KVB + 4 * hi;
#pragma unroll
            for (int s = 0; s < 2; ++s) {
                const int vlim = vlen - (kvb0 + s * 32);
#pragma unroll
                for (int r = 0; r < 16; ++r) {
                    const int rc = (r & 3) + 8 * (r >> 2);
                    acs[s][r] = (rc < vlim) ? acs[s][r] : NEG_INF;
                }
            }
        }

        // ---- row max: depth-5 tree + 1 shuffle ----
        float mx[8];
#pragma unroll
        for (int r = 0; r < 8; ++r)
            mx[r] = fmaxf(fmaxf(acs[0][r], acs[0][r + 8]),
                          fmaxf(acs[1][r], acs[1][r + 8]));
#pragma unroll
        for (int d = 4; d; d >>= 1)
#pragma unroll
            for (int r = 0; r < d; ++r) mx[r] = fmaxf(mx[r], mx[r + d]);
        float x = mx[0];
        x = fmaxf(x, __shfl_xor(x, 32, 64));

        // ---- T13 defer-max ----
        float mn = m;
        if (!__all(x <= m + 8.f)) {
            mn = fmaxf(m, x);
            const float alpha = exp2f(m - mn);   // m=-inf first -> 0
            m = mn;
            lsum *= alpha;
#pragma unroll
            for (int r = 0; r < 16; ++r) {
                const int rc = (r & 3) + 8 * (r >> 2);
                const float ar = __shfl(alpha, rc + 4 * hi, 64);
                acc_o[0][r] *= ar;
                acc_o[1][r] *= ar;
            }
        }

        // ---- P = exp2(s - mn); sum as tree + 1 shuffle ----
#pragma unroll
        for (int s = 0; s < 2; ++s)
#pragma unroll
            for (int r = 0; r < 16; ++r) acs[s][r] = exp2f(acs[s][r] - mn);
        float sm[8];
#pragma unroll
        for (int r = 0; r < 8; ++r)
            sm[r] = (acs[0][r] + acs[0][r + 8]) + (acs[1][r] + acs[1][r + 8]);
#pragma unroll
        for (int d = 4; d; d >>= 1)
#pragma unroll
            for (int r = 0; r < d; ++r) sm[r] += sm[r + d];
        float rs = sm[0];
        rs += __shfl_xor(rs, 32, 64);
        lsum += rs;

        // ---- P -> bf16 packs (16 cvt_pk) ----
        unsigned pk[2][4][2];
#pragma unroll
        for (int s = 0; s < 2; ++s)
#pragma unroll
            for (int be = 0; be < 4; ++be)
#pragma unroll
                for (int c = 0; c < 2; ++c)
                    asm("v_cvt_pk_bf16_f32 %0, %1, %2"
                        : "=v"(pk[s][be][c])
                        : "v"(acs[s][4 * be + 2 * c]),
                          "v"(acs[s][4 * be + 2 * c + 1]));

        // ---- O += P V: 8 permlane32_swap build A-frags in-register ----
        __builtin_amdgcn_s_setprio(1);
#pragma unroll
        for (int ks = 0; ks < 4; ++ks) {
            const int s = ks >> 1, g = ks & 1;
            unsigned w0 = pk[s][2 * g][0], w2 = pk[s][2 * g + 1][0];
            unsigned w1 = pk[s][2 * g][1], w3 = pk[s][2 * g + 1][1];
            asm("v_permlane32_swap_b32 %0, %1" : "+v"(w0), "+v"(w2));
            asm("v_permlane32_swap_b32 %0, %1" : "+v"(w1), "+v"(w3));
            union { unsigned u[4]; short8 s8; } pf;
            pf.u[0] = w0; pf.u[1] = w1; pf.u[2] = w2; pf.u[3] = w3;
#pragma unroll
            for (int t = 0; t < 2; ++t)
                acc_o[t] = __builtin_amdgcn_mfma_f32_32x32x16_bf16(
                    pf.s8, vfr[t * 4 + ks], acc_o[t], 0, 0, 0);
        }
        __builtin_amdgcn_s_setprio(0);
    };

    if (nh > 0) load_k(kf0, kvq);
    int it = 0;
    for (; it + 1 < nh; it += 2) {         // 2-phase unroll: static reg buffers
        body(kf0, kf1, it);
        body(kf1, kf0, it + 1);
    }
    if (it < nh) body(kf0, kf1, it);

    // ---- 4-way merge across KV quarters (shuffle-free) ----
    // every wave dumps its partial (C/D layout q=rc+4hi rows, d=t*32+l31 cols)
#pragma unroll
    for (int t = 0; t < 2; ++t)
#pragma unroll
        for (int r = 0; r < 16; ++r) {
            const int rc = (r & 3) + 8 * (r >> 2);
            mrg[qsub][kvq][rc + 4 * hi][t * 32 + l31] = acc_o[t][r];
        }
    if (lane < 32) mlb[qsub][kvq][l31] = float2{m, lsum};
    __syncthreads();

    // each wave outputs 8 q-rows: qsubo = wave>>2, q0 = (wave&3)*8
    {
        const int qsubo = wave >> 2;
        const int qq = (wave & 3) * 8 + (lane >> 3);
        const int dg = (lane & 7) * 8;
        float mi[4], li[4];
#pragma unroll
        for (int i = 0; i < 4; ++i) {
            const float2 c = mlb[qsubo][i][qq];
            mi[i] = c.x; li[i] = c.y;
        }
        const float M = fmaxf(fmaxf(mi[0], mi[1]), fmaxf(mi[2], mi[3]));
        float wgt[4], L = 0.f;
#pragma unroll
        for (int i = 0; i < 4; ++i) { wgt[i] = exp2f(mi[i] - M); L += li[i] * wgt[i]; }
        const float Linv = 1.f / L;
#pragma unroll
        for (int i = 0; i < 4; ++i) wgt[i] *= Linv;

        float4v o0 = {0.f, 0.f, 0.f, 0.f}, o1 = {0.f, 0.f, 0.f, 0.f};
#pragma unroll
        for (int i = 0; i < 4; ++i) {
            const float* src = &mrg[qsubo][i][qq][dg];
            float4v a = *reinterpret_cast<const float4v*>(src);
            float4v c = *reinterpret_cast<const float4v*>(src + 4);
#pragma unroll
            for (int j = 0; j < 4; ++j) { o0[j] += a[j] * wgt[i]; o1[j] += c[j] * wgt[i]; }
        }
        float* Ob = O + ((size_t)b * NQ + qt * 64 + qsubo * 32 + qq) * DH + dg;
        *reinterpret_cast<float4v*>(Ob)     = o0;
        *reinterpret_cast<float4v*>(Ob + 4) = o1;
    }
}

extern "C" void kernel_launch(void* const* d_in, const int* in_sizes, int n_in,
                              void* d_out, int out_size, void* d_ws, size_t ws_size,
                              hipStream_t stream) {
    const float* Q = (const float*)d_in[0];
    const float* K = (const float*)d_in[1];
    const float* V = (const float*)d_in[2];
    const int* vl  = (const int*)d_in[3];
    float* Out     = (float*)d_out;

    short* Kws = (short*)d_ws;
    short* Vws = Kws + (size_t)BATCH * NTILES * TILE_ELEMS;

    prep_kernel<<<dim3(BATCH * NTILES), dim3(256), 0, stream>>>(K, V, vl, Kws, Vws);
    attn_fwd_kernel<<<dim3(BATCH * (NQ / 64)), dim3(512), 0, stream>>>(
        Q, Kws, Vws, vl, Out);
}